// Round 7
// baseline (122.793 us; speedup 1.0000x reference)
//
#include <hip/hip_runtime.h>
#include <hip/hip_bf16.h>

// Problem constants (from reference): N=100000, F=128, E=640000, OUT=16
#define F_DIM 128
#define OUT_DIM 16

typedef _Float16 half8 __attribute__((ext_vector_type(8)));
typedef float floatx4 __attribute__((ext_vector_type(4)));
typedef unsigned short us8 __attribute__((ext_vector_type(8)));

__device__ __forceinline__ unsigned bf16_bits_rne(float f) {
    unsigned u = __builtin_bit_cast(unsigned, f);
    unsigned rounding = 0x7FFFu + ((u >> 16) & 1u);
    return (u + rounding) >> 16;          // RNE; NaN not possible here
}

// ---------------------------------------------------------------------------
// Kernel 1 (FUSED wprep+proj, 2 tiles/wave software-pipelined):
//   Phase 0: per-block LDS build of fp16 hi/lo weight fragments from W
//            (identical math to R5; R1 measured SQ_LDS_BANK_CONFLICT = 0).
//   Phase 1: each wave computes TWO 16-node tiles. All 16 h-loads (2 tiles
//            x 8 x 16B) are issued before any convert/MFMA so tile-1's loads
//            remain in flight under tile-0's compute — deepens the per-wave
//            memory pipeline that the one-tile-per-wave version lacked.
//   Block count halves (782): half the LDS-build prologues and W re-reads.
__global__ __launch_bounds__(256) void proj_fused2_kernel(
    const float* __restrict__ h, const float* __restrict__ W,
    const float* __restrict__ b,
    unsigned int* __restrict__ Pu16, unsigned int* __restrict__ Pv16, int N)
{
    __shared__ __align__(16) _Float16 sBhi[4096];
    __shared__ __align__(16) _Float16 sBlo[4096];
    for (int i = threadIdx.x; i < 4096; i += 256) {
        const int j  = i & 7;
        const int ln = (i >> 3) & 63;
        const int t  = (i >> 9) & 1;
        const int s  = (i >> 10) & 3;
        const int n2 = ln & 15;
        const int q2 = ln >> 4;
        const int k  = s * 32 + q2 * 8 + j;
        const float w = W[n2 * 256 + t * 128 + k];
        const _Float16 hi = (_Float16)w;
        sBhi[i] = hi;
        sBlo[i] = (_Float16)(w - (float)hi);
    }
    __syncthreads();

    const int lane = threadIdx.x & 63;
    const int wave = threadIdx.x >> 6;
    const int n = lane & 15;            // node within tile
    const int q = lane >> 4;            // quad: o-group and k-group selector
    const int row0 = blockIdx.x * 128 + wave * 32;   // tile A base
    const int row1 = row0 + 16;                      // tile B base
    if (row0 >= N) return;              // after the one barrier; none below
    const bool do1 = (row1 < N);        // N%32==0 -> uniform per wave

    int ar0 = row0 + n; if (ar0 >= N) ar0 = N - 1;
    int ar1 = row1 + n; if (ar1 >= N) ar1 = N - 1;   // clamped if !do1 (unstored)
    const float* hrow0 = h + (size_t)ar0 * F_DIM + q * 8;
    const float* hrow1 = h + (size_t)ar1 * F_DIM + q * 8;

    // All 16 h-loads issued up-front; tile-B loads in flight during tile-A
    // compute.
    floatx4 av0[8], av1[8];
    #pragma unroll
    for (int s = 0; s < 4; ++s) {
        av0[2 * s]     = *(const floatx4*)(hrow0 + s * 32);
        av0[2 * s + 1] = *(const floatx4*)(hrow0 + s * 32 + 4);
        av1[2 * s]     = *(const floatx4*)(hrow1 + s * 32);
        av1[2 * s + 1] = *(const floatx4*)(hrow1 + s * 32 + 4);
    }

    const floatx4 bv = *(const floatx4*)(b + 4 * q);   // b[4q+reg]

    floatx4 c0a = {0.f, 0.f, 0.f, 0.f};   // tile A, u half
    floatx4 c1a = {0.f, 0.f, 0.f, 0.f};   // tile A, v half
    floatx4 c0b = {0.f, 0.f, 0.f, 0.f};   // tile B, u half
    floatx4 c1b = {0.f, 0.f, 0.f, 0.f};   // tile B, v half

    #pragma unroll
    for (int s = 0; s < 4; ++s) {
        half8 ah, al;
        #pragma unroll
        for (int j = 0; j < 8; ++j) {     // static indexing after unroll
            const float x = (j < 4) ? av0[2 * s][j] : av0[2 * s + 1][j - 4];
            const _Float16 hi = (_Float16)x;
            ah[j] = hi;
            al[j] = (_Float16)(x - (float)hi);
        }
        const int base0 = (s * 2 + 0) * 512 + lane * 8;
        const int base1 = (s * 2 + 1) * 512 + lane * 8;
        const half8 wh0 = *(const half8*)(sBhi + base0);
        const half8 wl0 = *(const half8*)(sBlo + base0);
        const half8 wh1 = *(const half8*)(sBhi + base1);
        const half8 wl1 = *(const half8*)(sBlo + base1);

        c0a = __builtin_amdgcn_mfma_f32_16x16x32_f16(wh0, ah, c0a, 0, 0, 0);
        c0a = __builtin_amdgcn_mfma_f32_16x16x32_f16(wl0, ah, c0a, 0, 0, 0);
        c0a = __builtin_amdgcn_mfma_f32_16x16x32_f16(wh0, al, c0a, 0, 0, 0);
        c1a = __builtin_amdgcn_mfma_f32_16x16x32_f16(wh1, ah, c1a, 0, 0, 0);
        c1a = __builtin_amdgcn_mfma_f32_16x16x32_f16(wl1, ah, c1a, 0, 0, 0);
        c1a = __builtin_amdgcn_mfma_f32_16x16x32_f16(wh1, al, c1a, 0, 0, 0);
    }

    #pragma unroll
    for (int s = 0; s < 4; ++s) {
        half8 ah, al;
        #pragma unroll
        for (int j = 0; j < 8; ++j) {
            const float x = (j < 4) ? av1[2 * s][j] : av1[2 * s + 1][j - 4];
            const _Float16 hi = (_Float16)x;
            ah[j] = hi;
            al[j] = (_Float16)(x - (float)hi);
        }
        const int base0 = (s * 2 + 0) * 512 + lane * 8;
        const int base1 = (s * 2 + 1) * 512 + lane * 8;
        const half8 wh0 = *(const half8*)(sBhi + base0);
        const half8 wl0 = *(const half8*)(sBlo + base0);
        const half8 wh1 = *(const half8*)(sBhi + base1);
        const half8 wl1 = *(const half8*)(sBlo + base1);

        c0b = __builtin_amdgcn_mfma_f32_16x16x32_f16(wh0, ah, c0b, 0, 0, 0);
        c0b = __builtin_amdgcn_mfma_f32_16x16x32_f16(wl0, ah, c0b, 0, 0, 0);
        c0b = __builtin_amdgcn_mfma_f32_16x16x32_f16(wh0, al, c0b, 0, 0, 0);
        c1b = __builtin_amdgcn_mfma_f32_16x16x32_f16(wh1, ah, c1b, 0, 0, 0);
        c1b = __builtin_amdgcn_mfma_f32_16x16x32_f16(wl1, ah, c1b, 0, 0, 0);
        c1b = __builtin_amdgcn_mfma_f32_16x16x32_f16(wh1, al, c1b, 0, 0, 0);
    }

    const int node0 = row0 + n;
    if (node0 < N) {
        unsigned u0 = bf16_bits_rne(c0a[0] + bv[0]) | (bf16_bits_rne(c0a[1] + bv[1]) << 16);
        unsigned u1 = bf16_bits_rne(c0a[2] + bv[2]) | (bf16_bits_rne(c0a[3] + bv[3]) << 16);
        unsigned v0 = bf16_bits_rne(c1a[0]) | (bf16_bits_rne(c1a[1]) << 16);
        unsigned v1 = bf16_bits_rne(c1a[2]) | (bf16_bits_rne(c1a[3]) << 16);
        const size_t base = (size_t)node0 * 8 + 2 * q;
        Pu16[base]     = u0;
        Pu16[base + 1] = u1;
        Pv16[base]     = v0;
        Pv16[base + 1] = v1;
    }
    const int node1 = row1 + n;
    if (do1 && node1 < N) {
        unsigned u0 = bf16_bits_rne(c0b[0] + bv[0]) | (bf16_bits_rne(c0b[1] + bv[1]) << 16);
        unsigned u1 = bf16_bits_rne(c0b[2] + bv[2]) | (bf16_bits_rne(c0b[3] + bv[3]) << 16);
        unsigned v0 = bf16_bits_rne(c1b[0]) | (bf16_bits_rne(c1b[1]) << 16);
        unsigned v1 = bf16_bits_rne(c1b[2]) | (bf16_bits_rne(c1b[3]) << 16);
        const size_t base = (size_t)node1 * 8 + 2 * q;
        Pu16[base]     = u0;
        Pu16[base + 1] = u1;
        Pv16[base]     = v0;
        Pv16[base + 1] = v1;
    }
}

// ---------------------------------------------------------------------------
// Kernel 2: out[e][o] = Pu[src[e]][o] + Pv[dst[e]][o]   (bias already in Pu)
// R4's proven store geometry, deepened to 8 items/thread: 8 independent
// {idx -> gather} chains, 16 scattered 16B table loads in flight, 8 store
// regions each with the R0-coalesced interleave (adjacent lanes adjacent,
// 32B/lane — the pattern measured free of write amplification).
__global__ __launch_bounds__(256) void gather8_kernel(
    const unsigned short* __restrict__ Pu, const unsigned short* __restrict__ Pv,
    const int* __restrict__ src, const int* __restrict__ dst,
    float* __restrict__ out, int E)
{
    const int total = 2 * E;                    // item count
    const int T = (total + 7) >> 3;             // items per eighth = threads
    const int t = blockIdx.x * blockDim.x + threadIdx.x;
    if (t >= T) return;

    int it[8];
    #pragma unroll
    for (int k = 0; k < 8; ++k) it[k] = t + k * T;

    // Phase A: all index loads issued together (independent, coalesced;
    // adjacent lanes share e = item>>1 -> broadcast within the pair).
    int si[8], di[8];
    #pragma unroll
    for (int k = 0; k < 8; ++k) {
        const int e = (it[k] < total) ? (it[k] >> 1) : 0;
        si[k] = src[e];
        di[k] = dst[e];
    }

    // Phase B: all 16 scattered 16B table gathers in flight together.
    us8 pu[8], pv[8];
    #pragma unroll
    for (int k = 0; k < 8; ++k) {
        const int q = it[k] & 1;
        pu[k] = *(const us8*)(Pu + (size_t)si[k] * 16 + q * 8);
        pv[k] = *(const us8*)(Pv + (size_t)di[k] * 16 + q * 8);
    }

    // Phase C: convert + store (proven geometry per region).
    #pragma unroll
    for (int k = 0; k < 8; ++k) {
        if (it[k] >= total) continue;
        floatx4 r0, r1;
        #pragma unroll
        for (int j = 0; j < 4; ++j) {
            r0[j] = __uint_as_float((unsigned)pu[k][j] << 16)
                  + __uint_as_float((unsigned)pv[k][j] << 16);
            r1[j] = __uint_as_float((unsigned)pu[k][j + 4] << 16)
                  + __uint_as_float((unsigned)pv[k][j + 4] << 16);
        }
        floatx4* o = (floatx4*)out + (size_t)it[k] * 2;
        __builtin_nontemporal_store(r0, o);
        __builtin_nontemporal_store(r1, o + 1);
    }
}

// Fallback (only if workspace too small): direct per-(edge,out) dot, fp32.
__global__ __launch_bounds__(256) void direct_kernel(
    const float* __restrict__ h, const int* __restrict__ src,
    const int* __restrict__ dst, const float* __restrict__ W,
    const float* __restrict__ b, float* __restrict__ out, int E)
{
    const int tid = blockIdx.x * blockDim.x + threadIdx.x;
    if (tid >= E * OUT_DIM) return;
    const int e = tid >> 4;
    const int o = tid & 15;
    const float* hu = h + (size_t)src[e] * F_DIM;
    const float* hv = h + (size_t)dst[e] * F_DIM;
    const float* wu = W + (size_t)o * 256;
    const float* wv = wu + 128;
    float acc = b[o];
    for (int k = 0; k < 128; ++k) acc = fmaf(hu[k], wu[k], acc);
    for (int k = 0; k < 128; ++k) acc = fmaf(hv[k], wv[k], acc);
    out[tid] = acc;
}

extern "C" void kernel_launch(void* const* d_in, const int* in_sizes, int n_in,
                              void* d_out, int out_size, void* d_ws, size_t ws_size,
                              hipStream_t stream) {
    const float* h   = (const float*)d_in[0];
    const int*   src = (const int*)d_in[1];
    const int*   dst = (const int*)d_in[2];
    const float* W   = (const float*)d_in[3];
    const float* b   = (const float*)d_in[4];
    float* out = (float*)d_out;

    const int N = in_sizes[0] / F_DIM;     // 100000
    const int E = in_sizes[1];             // 640000

    const size_t p16_bytes = (size_t)N * 8 * sizeof(unsigned);    // 3.2 MB
    const size_t p16_al    = (p16_bytes + 255) & ~(size_t)255;

    if (ws_size >= 2 * p16_al) {
        unsigned int* Pu16 = (unsigned int*)d_ws;
        unsigned int* Pv16 = (unsigned int*)((char*)d_ws + p16_al);

        const int blocks1 = (N + 127) / 128;            // 782 (2 tiles/wave)
        proj_fused2_kernel<<<blocks1, 256, 0, stream>>>(h, W, b, Pu16, Pv16, N);

        const int threads2 = (2 * E + 7) / 8;           // 8 items per thread
        const int blocks2  = (threads2 + 255) / 256;    // 625 blocks
        gather8_kernel<<<blocks2, 256, 0, stream>>>(
            (const unsigned short*)Pu16, (const unsigned short*)Pv16,
            src, dst, out, E);
    } else {
        const int total  = E * OUT_DIM;
        const int blocks = (total + 255) / 256;
        direct_kernel<<<blocks, 256, 0, stream>>>(h, src, dst, W, b, out, E);
    }
}